// Round 10
// baseline (183.954 us; speedup 1.0000x reference)
//
#include <hip/hip_runtime.h>

#define BATCH 256
#define SEQ   256
#define CDIM  384
#define HDIM  64

typedef __attribute__((ext_vector_type(8))) short bf16x8;
typedef __attribute__((ext_vector_type(4))) float f32x4;

__device__ __forceinline__ unsigned f2bf(float f) {
  union { float f; unsigned u; } v; v.f = f;
  unsigned r = v.u + 0x7FFFu + ((v.u >> 16) & 1u);   // RNE
  return r >> 16;
}

// ---------------------------------------------------------------------------
// kernel 0 (unchanged): WTf = [Wq|Wk|Wv]^T in MFMA fragment order.
//   record (ks,nt) = 1024 B at (ks*12+nt)*1024; lane holds 16 B at lane*16.
// ---------------------------------------------------------------------------
__global__ void wtrans_kernel(const float* __restrict__ Wk, const float* __restrict__ Wq,
                              const float* __restrict__ Wv, unsigned short* __restrict__ WTf) {
  int gid = blockIdx.x * 256 + threadIdx.x;
  if (gid >= 192 * CDIM) return;
  int n = gid / CDIM, kk = gid - n * CDIM;
  const float* W = (n < 64) ? Wq : (n < 128) ? Wk : Wv;
  int nt = n >> 4, ln = n & 15, ks = kk >> 5, sub = (kk >> 3) & 3, j = kk & 7;
  int lane = ln + 16 * sub;
  WTf[(((size_t)ks * 12 + nt) * 64 + lane) * 8 + j] =
      (unsigned short)f2bf(W[kk * HDIM + (n & 63)]);
}

// ---------------------------------------------------------------------------
// kernel 1: fused proj+attention, TWO CO-RESIDENT BLOCKS PER CU.
//   Rounds 3-9: six within-block schedules all pinned at ~56 us; the shared
//   trait was 1 block/CU (every drain idles the whole CU).  This version:
//   512 blocks x 512 thr, LDS 75.5 KB -> 2 blocks/CU; when one block sits in
//   a barrier/stage-drain the sibling's waves fill the pipes (m114).
//   Zero cross-block deps: lower block (bid<256) = proj rows 0-127 + attn
//   m-tiles 0-7 (causal: needs only kv 0-127).  Upper block = proj rows
//   128-255 (full) + DUPLICATE kv-only proj of rows 0-127 + attn m-tiles
//   8-15.  Duplication (1.33x MFMA, 1.5x x-reads, partly L2-shared since
//   bid k and k+256 land on the same CU) buys total independence.
//   W staged per-ks (12 KB region, 12 cycles/pass, uniform vmcnt(2) counted
//   waits; x register ping-pong rides across).  LDS diet: q never goes to
//   LDS (bounced via wave-private PL in two 32-col halves); KL pad 68,
//   VT pad 260.  Accumulation order identical to the verified r3 kernel.
// ---------------------------------------------------------------------------
__global__ __launch_bounds__(512, 4) void fused_kernel(
    const float* __restrict__ x, const unsigned short* __restrict__ WTf,
    float* __restrict__ out) {
  __shared__ __align__(16) char L[77312];
  const int tid = threadIdx.x, bid = blockIdx.x;
  const int b = bid & 255;
  const bool up = bid >= 256;
  const int w = tid >> 6, lane = tid & 63;
  const int ln15 = lane & 15, quad = lane >> 4;

  // region map: [0,12288) W-stage (dead after proj) | after proj:
  // KL[256][68] @0 (34816 B) | VT[64][260] @34816 (33280 B) | PL @68096.
  unsigned short (*KL)[68]  = (unsigned short(*)[68])L;
  unsigned short (*VT)[260] = (unsigned short(*)[260])(L + 34816);
  unsigned short (*PLw)[36] = (unsigned short(*)[36])(L + 68096 + w * 1152);

#define WDMA(GREC, LREC)                                                      \
  __builtin_amdgcn_global_load_lds(                                           \
      (const __attribute__((address_space(1))) unsigned*)((const char*)WTf +  \
          (size_t)(GREC) * 1024 + lane * 16),                                 \
      (__attribute__((address_space(3))) unsigned*)(L + (LREC) * 1024 + lane * 16), \
      16, 0, 0);

  // one proj pass: 12 cycles of {W-DMA(ks i) -> prefetch x(ks i+1) ->
  // vmcnt(2) [retires own W + prev x; leaves new x in flight] -> barrier ->
  // 12(or 8) MFMAs -> barrier}.  NTB/NTC select the nt (output-col) range.
#define PROJPASS(ACC, NTB, NTC, XR)                                           \
  {                                                                           \
    float4 Qa[2], Qb[2];                                                      \
    Qa[0] = *(const float4*)((XR) + 0);                                       \
    Qa[1] = *(const float4*)((XR) + 4);                                       \
    _Pragma("unroll")                                                         \
    for (int i = 0; i < 12; ++i) {                                            \
      WDMA(i * 12 + (NTB) + w, w)                                             \
      if ((NTC) == 12 && w < 4) { WDMA(i * 12 + 8 + w, 8 + w) }               \
      if (i < 11) {                                                           \
        if (i & 1) {                                                          \
          Qa[0] = *(const float4*)((XR) + (i + 1) * 32);                      \
          Qa[1] = *(const float4*)((XR) + (i + 1) * 32 + 4);                  \
        } else {                                                              \
          Qb[0] = *(const float4*)((XR) + (i + 1) * 32);                      \
          Qb[1] = *(const float4*)((XR) + (i + 1) * 32 + 4);                  \
        }                                                                     \
      }                                                                       \
      __builtin_amdgcn_sched_barrier(0);                                      \
      if (i < 11) { asm volatile("s_waitcnt vmcnt(2)" ::: "memory"); }        \
      else        { asm volatile("s_waitcnt vmcnt(0)" ::: "memory"); }        \
      __builtin_amdgcn_s_barrier();                                           \
      __builtin_amdgcn_sched_barrier(0);                                      \
      {                                                                       \
        float4 c0 = (i & 1) ? Qb[0] : Qa[0];                                  \
        float4 c1 = (i & 1) ? Qb[1] : Qa[1];                                  \
        bf16x8 t;                                                             \
        t[0] = (short)f2bf(c0.x); t[1] = (short)f2bf(c0.y);                   \
        t[2] = (short)f2bf(c0.z); t[3] = (short)f2bf(c0.w);                   \
        t[4] = (short)f2bf(c1.x); t[5] = (short)f2bf(c1.y);                   \
        t[6] = (short)f2bf(c1.z); t[7] = (short)f2bf(c1.w);                   \
        _Pragma("unroll")                                                     \
        for (int nt = 0; nt < (NTC); ++nt) {                                  \
          bf16x8 aw = *(const bf16x8*)(L + nt * 1024 + lane * 16);            \
          ACC[nt] = __builtin_amdgcn_mfma_f32_16x16x32_bf16(aw, t, ACC[nt], 0, 0, 0); \
        }                                                                     \
      }                                                                       \
      __builtin_amdgcn_sched_barrier(0);                                      \
      __builtin_amdgcn_s_barrier();                                           \
      __builtin_amdgcn_sched_barrier(0);                                      \
    }                                                                         \
  }

  // k/v handoff: ACCARR[OFF..OFF+3]=k frags, [OFF+4..OFF+7]=v frags.
#define HANDKV(ACCARR, OFF, TROW)                                             \
  {                                                                           \
    _Pragma("unroll")                                                         \
    for (int j = 0; j < 4; ++j) {                                             \
      f32x4 a = ACCARR[(OFF) + j];                                            \
      unsigned p0 = f2bf(a[0]) | (f2bf(a[1]) << 16);                          \
      unsigned p1 = f2bf(a[2]) | (f2bf(a[3]) << 16);                          \
      *(uint2*)&KL[TROW][j * 16 + quad * 4] = (uint2){p0, p1};                \
    }                                                                         \
    _Pragma("unroll")                                                         \
    for (int j = 0; j < 4; ++j) {                                             \
      f32x4 a = ACCARR[(OFF) + 4 + j];                                        \
      const int h = j * 16 + quad * 4;                                        \
      _Pragma("unroll")                                                       \
      for (int i2 = 0; i2 < 4; ++i2)                                          \
        VT[h + i2][TROW] = (unsigned short)f2bf(a[i2]);                       \
    }                                                                         \
  }

  // ---- proj ---------------------------------------------------------------
  f32x4 accA[12];
  #pragma unroll
  for (int nt = 0; nt < 12; ++nt) accA[nt] = (f32x4){0.f, 0.f, 0.f, 0.f};

  if (up) {
    f32x4 accB[8];
    #pragma unroll
    for (int j = 0; j < 8; ++j) accB[j] = (f32x4){0.f, 0.f, 0.f, 0.f};
    // pass B: duplicate kv-only proj of rows 0-127 (nt 4..11)
    const float* xrB = x + ((size_t)(b * 256) + w * 16 + ln15) * CDIM + quad * 8;
    PROJPASS(accB, 4, 8, xrB)
    // pass A: full proj of rows 128-255
    const float* xrA = xrB + (size_t)128 * CDIM;
    PROJPASS(accA, 0, 12, xrA)
    // handoffs (W region dead; trailing barrier of last cycle passed)
    const int trB = w * 16 + ln15;
    const int trA = 128 + w * 16 + ln15;
    HANDKV(accA, 4, trA)
    HANDKV(accB, 0, trB)
  } else {
    const float* xrL = x + ((size_t)(b * 256) + w * 16 + ln15) * CDIM + quad * 8;
    PROJPASS(accA, 0, 12, xrL)
    const int trL = w * 16 + ln15;
    HANDKV(accA, 4, trL)
  }
  __syncthreads();

  // ---- attention: wave w owns m-tile (up ? 8+w : w) -----------------------
  {
    const int mt = up ? (8 + w) : w;
    const int t0 = mt * 16;
    const int NT = (mt | 1) + 1;                 // even # of 16-wide s-tiles

    // q-bounce: accA[0..3] -> PL (wave-private, DS in-order) -> A-frags
    bf16x8 aq[2];
    #pragma unroll
    for (int half = 0; half < 2; ++half) {
      #pragma unroll
      for (int n2 = 0; n2 < 2; ++n2) {
        f32x4 a = accA[half * 2 + n2];
        unsigned p0 = f2bf(a[0]) | (f2bf(a[1]) << 16);
        unsigned p1 = f2bf(a[2]) | (f2bf(a[3]) << 16);
        *(uint2*)&PLw[ln15][n2 * 16 + quad * 4] = (uint2){p0, p1};
      }
      aq[half] = *(const bf16x8*)&PLw[ln15][quad * 8];
      __builtin_amdgcn_sched_barrier(0);         // pin write/read issue order
    }

    float sv[16][4];
    #pragma unroll
    for (int nt = 0; nt < 16; ++nt) {
      if (nt < NT) {
        f32x4 a2 = (f32x4){0.f, 0.f, 0.f, 0.f};
        #pragma unroll
        for (int ks = 0; ks < 2; ++ks) {
          bf16x8 bf = *(const bf16x8*)&KL[nt * 16 + ln15][ks * 32 + quad * 8];
          a2 = __builtin_amdgcn_mfma_f32_16x16x32_bf16(aq[ks], bf, a2, 0, 0, 0);
        }
        int colg = nt * 16 + ln15;
        #pragma unroll
        for (int i = 0; i < 4; ++i) {
          int rowg = t0 + quad * 4 + i;
          sv[nt][i] = (colg <= rowg) ? a2[i] * 0.125f : -3.0e38f;   // 1/sqrt(64)
        }
      }
    }
    float mx[4] = {-3.0e38f, -3.0e38f, -3.0e38f, -3.0e38f};
    #pragma unroll
    for (int nt = 0; nt < 16; ++nt)
      if (nt < NT) {
        #pragma unroll
        for (int i = 0; i < 4; ++i) mx[i] = fmaxf(mx[i], sv[nt][i]);
      }
    #pragma unroll
    for (int i = 0; i < 4; ++i) {                // reduce across 16-lane group
      mx[i] = fmaxf(mx[i], __shfl_xor(mx[i], 8, 64));
      mx[i] = fmaxf(mx[i], __shfl_xor(mx[i], 4, 64));
      mx[i] = fmaxf(mx[i], __shfl_xor(mx[i], 2, 64));
      mx[i] = fmaxf(mx[i], __shfl_xor(mx[i], 1, 64));
    }
    float sm[4] = {0.f, 0.f, 0.f, 0.f};
    #pragma unroll
    for (int nt = 0; nt < 16; ++nt)
      if (nt < NT) {
        #pragma unroll
        for (int i = 0; i < 4; ++i) {
          float e = __expf(sv[nt][i] - mx[i]);
          sv[nt][i] = e;
          sm[i] += e;
        }
      }
    #pragma unroll
    for (int i = 0; i < 4; ++i) {
      sm[i] += __shfl_xor(sm[i], 8, 64);
      sm[i] += __shfl_xor(sm[i], 4, 64);
      sm[i] += __shfl_xor(sm[i], 2, 64);
      sm[i] += __shfl_xor(sm[i], 1, 64);
    }
    float inv[4];
    #pragma unroll
    for (int i = 0; i < 4; ++i) inv[i] = 1.0f / sm[i];

    // PV in 32-wide K chunks via the wave-private P buffer (DS in-order).
    f32x4 o[4];
    #pragma unroll
    for (int ont = 0; ont < 4; ++ont) o[ont] = (f32x4){0.f, 0.f, 0.f, 0.f};

    #pragma unroll
    for (int kc = 0; kc < 8; ++kc) {
      if (kc * 2 < NT) {
        #pragma unroll
        for (int half = 0; half < 2; ++half) {
          int nt = kc * 2 + half;
          #pragma unroll
          for (int i = 0; i < 4; ++i)
            PLw[quad * 4 + i][half * 16 + ln15] =
                (unsigned short)f2bf(sv[nt][i] * inv[i]);
        }
        bf16x8 pa = *(const bf16x8*)&PLw[ln15][quad * 8];
        #pragma unroll
        for (int ont = 0; ont < 4; ++ont) {
          bf16x8 vb = *(const bf16x8*)&VT[ont * 16 + ln15][kc * 32 + quad * 8];
          o[ont] = __builtin_amdgcn_mfma_f32_16x16x32_bf16(pa, vb, o[ont], 0, 0, 0);
        }
      }
    }

    #pragma unroll
    for (int ont = 0; ont < 4; ++ont) {
      int h = ont * 16 + ln15;
      #pragma unroll
      for (int i = 0; i < 4; ++i)
        out[(size_t)(b * 256 + t0 + quad * 4 + i) * HDIM + h] = o[ont][i];
    }
  }
}

// ---------------------------------------------------------------------------
// ws layout: only WTf (147456 B).
// ---------------------------------------------------------------------------
extern "C" void kernel_launch(void* const* d_in, const int* in_sizes, int n_in,
                              void* d_out, int out_size, void* d_ws, size_t ws_size,
                              hipStream_t stream) {
  const float* x  = (const float*)d_in[0];
  const float* Wk = (const float*)d_in[1];
  const float* Wq = (const float*)d_in[2];
  const float* Wv = (const float*)d_in[3];
  float* out = (float*)d_out;

  unsigned short* WTf = (unsigned short*)d_ws;   // 147456 B

  wtrans_kernel<<<(192 * CDIM + 255) / 256, 256, 0, stream>>>(Wk, Wq, Wv, WTf);
  fused_kernel<<<512, 512, 0, stream>>>(x, WTf, out);
}

// Round 11
// 172.168 us; speedup vs baseline: 1.0685x; 1.0685x over previous
//
#include <hip/hip_runtime.h>

#define BATCH 256
#define SEQ   256
#define CDIM  384
#define HDIM  64

typedef __attribute__((ext_vector_type(8))) short bf16x8;
typedef __attribute__((ext_vector_type(4))) float f32x4;

__device__ __forceinline__ unsigned f2bf(float f) {
  union { float f; unsigned u; } v; v.f = f;
  unsigned r = v.u + 0x7FFFu + ((v.u >> 16) & 1u);   // RNE
  return r >> 16;
}

// ---------------------------------------------------------------------------
// kernel 0 (unchanged): WTf = [Wq|Wk|Wv]^T in MFMA fragment order.
//   record (ks,nt) = 1024 B at (ks*12+nt)*1024; lane holds 16 B at lane*16.
//   ks 0..5 = bytes [0,73728) (half 1), ks 6..11 = [73728,147456) (half 2).
// ---------------------------------------------------------------------------
__global__ void wtrans_kernel(const float* __restrict__ Wk, const float* __restrict__ Wq,
                              const float* __restrict__ Wv, unsigned short* __restrict__ WTf) {
  int gid = blockIdx.x * 256 + threadIdx.x;
  if (gid >= 192 * CDIM) return;
  int n = gid / CDIM, kk = gid - n * CDIM;
  const float* W = (n < 64) ? Wq : (n < 128) ? Wk : Wv;
  int nt = n >> 4, ln = n & 15, ks = kk >> 5, sub = (kk >> 3) & 3, j = kk & 7;
  int lane = ln + 16 * sub;
  WTf[(((size_t)ks * 12 + nt) * 64 + lane) * 8 + j] =
      (unsigned short)f2bf(W[kk * HDIM + (n & 63)]);
}

// ---------------------------------------------------------------------------
// kernel 1: fused proj+attention — FAT WAVES + DMA x-STREAM (combined).
//   r6 (DMA, 16 thin waves) and r8 (fat waves, register staging) each fixed
//   one half of the stall and failed on the other: thin waves double W
//   ds_read volume and under-cover HBM latency per PSTEP; register staging
//   collapses under the RA.  This kernel: 8 waves x 32 rows (W DS volume
//   halved, per-PSTEP compute ~doubled) with x streamed via global_load_lds
//   into per-wave private 2x4KB double buffers (depth is RA-proof, zero
//   VGPR) and counted per-wave vmcnt — NO barriers in the ks loop.
//   W staged in halves (region [0,73728), restaged once behind
//   barrier+vmcnt(0)+barrier).  x chunks XOR-swizzled via pre-swizzled
//   global source (linear DMA dest, same XOR on read) — r6-verified pattern.
//   LDS: W 73728 + x dbuf 8x8192 = 139264 B; attn aliases [0,125952).
//   Handoff = r8-verified; attention = r7-verified {w, 15-w} two-tile loop.
//   Accumulation order identical (ks ascending) -> absmax unchanged.
// ---------------------------------------------------------------------------
__global__ __launch_bounds__(512, 2) void fused_kernel(
    const float* __restrict__ x, const unsigned short* __restrict__ WTf,
    float* __restrict__ out) {
  __shared__ __align__(16) char L[139264];
  const int tid = threadIdx.x, b = blockIdx.x;
  const int w = tid >> 6, lane = tid & 63;
  const int ln15 = lane & 15, quad = lane >> 4;

  // ---- W half-1 DMAs (issued FIRST = oldest in the per-wave vmcnt FIFO) --
  // 72 records of 1024 B; wave w takes records w*9 .. w*9+8 (9 each).
  {
    #pragma unroll
    for (int i = 0; i < 9; ++i) {
      int rec = w * 9 + i;
      __builtin_amdgcn_global_load_lds(
          (const __attribute__((address_space(1))) unsigned*)((const char*)WTf + (size_t)rec * 1024 + lane * 16),
          (__attribute__((address_space(3))) unsigned*)(L + (size_t)rec * 1024 + lane * 16),
          16, 0, 0);
    }
  }
  __builtin_amdgcn_sched_barrier(0);

  // ---- x DMA addressing (XOR-swizzled global source, linear LDS dest) ----
  // chunk K = this wave's 32 rows x 32 k-floats = 4096 B, four 1024-B DMAs
  // (instr j covers rows 8j..8j+7).  LDS slot (j, r0=lane>>3, g'=lane&7)
  // holds row 8j+r0, col-group cg = g' ^ r0 (16-B groups).
  const int r0 = lane >> 3;
  const int cgs = (lane & 7) ^ r0;
  const char* xsrc = (const char*)x +
      ((size_t)(b * 256 + w * 32 + r0) * CDIM + cgs * 4) * 4;
  char* xbuf = L + 73728 + w * 8192;

#define XDMA(K, S)                                                            \
  {                                                                           \
    _Pragma("unroll")                                                         \
    for (int j = 0; j < 4; ++j) {                                             \
      __builtin_amdgcn_global_load_lds(                                       \
          (const __attribute__((address_space(1))) unsigned*)(xsrc +          \
              (size_t)j * 8 * CDIM * 4 + (K) * 128),                          \
          (__attribute__((address_space(3))) unsigned*)(xbuf + (S) * 4096 +   \
              j * 1024 + lane * 16),                                          \
          16, 0, 0);                                                          \
    }                                                                         \
  }

  // prologue: chunk 0 in flight behind the W half-1 DMAs
  XDMA(0, 0)
  __builtin_amdgcn_sched_barrier(0);
  // 9 W + 4 x outstanding; vmcnt(4) retires exactly the 9 oldest = all W1.
  asm volatile("s_waitcnt vmcnt(4)" ::: "memory");
  __builtin_amdgcn_s_barrier();
  __builtin_amdgcn_sched_barrier(0);

  // read offsets within a chunk (XOR matches the DMA source swizzle)
  const int roA = ln15 * 128 + (((2 * quad) ^ (ln15 & 7)) * 16);
  const int roB = ln15 * 128 + ((((2 * quad) + 1) ^ (ln15 & 7)) * 16);

  f32x4 acc0[12], acc1[12];
  #pragma unroll
  for (int nt = 0; nt < 12; ++nt) {
    acc0[nt] = (f32x4){0.f, 0.f, 0.f, 0.f};
    acc1[nt] = (f32x4){0.f, 0.f, 0.f, 0.f};
  }

  // PSTEP(K): issue chunk K+1 (other buffer; its last reader was PSTEP(K-1),
  // whose ds_reads are register-consumed => complete), retire chunk K
  // (vmcnt<=4 leaves only K+1's 4 DMAs), read rg0/rg1, 24 MFMAs.
#define PSTEP(K, KIDX, VMN, ISSUE)                                            \
  {                                                                           \
    ISSUE                                                                     \
    __builtin_amdgcn_sched_barrier(0);                                        \
    asm volatile("s_waitcnt vmcnt(" #VMN ")" ::: "memory");                   \
    __builtin_amdgcn_sched_barrier(0);                                        \
    const char* cb = xbuf + ((K) & 1) * 4096;                                 \
    float4 fa0 = *(const float4*)(cb + roA);                                  \
    float4 fb0 = *(const float4*)(cb + roB);                                  \
    float4 fa1 = *(const float4*)(cb + 2048 + roA);                           \
    float4 fb1 = *(const float4*)(cb + 2048 + roB);                           \
    bf16x8 t0, t1;                                                            \
    t0[0] = (short)f2bf(fa0.x); t0[1] = (short)f2bf(fa0.y);                   \
    t0[2] = (short)f2bf(fa0.z); t0[3] = (short)f2bf(fa0.w);                   \
    t0[4] = (short)f2bf(fb0.x); t0[5] = (short)f2bf(fb0.y);                   \
    t0[6] = (short)f2bf(fb0.z); t0[7] = (short)f2bf(fb0.w);                   \
    t1[0] = (short)f2bf(fa1.x); t1[1] = (short)f2bf(fa1.y);                   \
    t1[2] = (short)f2bf(fa1.z); t1[3] = (short)f2bf(fa1.w);                   \
    t1[4] = (short)f2bf(fb1.x); t1[5] = (short)f2bf(fb1.y);                   \
    t1[6] = (short)f2bf(fb1.z); t1[7] = (short)f2bf(fb1.w);                   \
    _Pragma("unroll")                                                         \
    for (int nt = 0; nt < 12; ++nt) {                                         \
      bf16x8 aw = *(const bf16x8*)(L + ((KIDX) * 12 + nt) * 1024 + lane * 16); \
      acc0[nt] = __builtin_amdgcn_mfma_f32_16x16x32_bf16(aw, t0, acc0[nt], 0, 0, 0); \
      acc1[nt] = __builtin_amdgcn_mfma_f32_16x16x32_bf16(aw, t1, acc1[nt], 0, 0, 0); \
    }                                                                         \
  }

  PSTEP(0, 0, 4, XDMA(1, 1))
  PSTEP(1, 1, 4, XDMA(2, 0))
  PSTEP(2, 2, 4, XDMA(3, 1))
  PSTEP(3, 3, 4, XDMA(4, 0))
  PSTEP(4, 4, 4, XDMA(5, 1))
  PSTEP(5, 5, 4, XDMA(6, 0))

  // ---- W half-2 swap: region A dead (all half-1 reads register-consumed) -
  __builtin_amdgcn_sched_barrier(0);
  __builtin_amdgcn_s_barrier();
  {
    #pragma unroll
    for (int i = 0; i < 9; ++i) {
      int rec = w * 9 + i;
      __builtin_amdgcn_global_load_lds(
          (const __attribute__((address_space(1))) unsigned*)((const char*)WTf + 73728 + (size_t)rec * 1024 + lane * 16),
          (__attribute__((address_space(3))) unsigned*)(L + (size_t)rec * 1024 + lane * 16),
          16, 0, 0);
    }
  }
  asm volatile("s_waitcnt vmcnt(0)" ::: "memory");   // lands W2 + chunk 6
  __builtin_amdgcn_s_barrier();
  __builtin_amdgcn_sched_barrier(0);

  PSTEP(6,  0, 4, XDMA(7, 1))
  PSTEP(7,  1, 4, XDMA(8, 0))
  PSTEP(8,  2, 4, XDMA(9, 1))
  PSTEP(9,  3, 4, XDMA(10, 0))
  PSTEP(10, 4, 4, XDMA(11, 1))
  PSTEP(11, 5, 0, )

  __syncthreads();            // all waves done -> LDS reusable for attn

  // ---- handoff: q/k/v -> LDS (aliased; r8-verified layout) ----------------
  unsigned short (*QL)[72]  = (unsigned short(*)[72])L;                   // [0,36864)
  unsigned short (*KL)[72]  = (unsigned short(*)[72])(L + 36864);         // [36864,73728)
  unsigned short (*VT)[264] = (unsigned short(*)[264])(L + 73728);        // [73728,107520)
  unsigned short (*PL)[36]  = (unsigned short(*)[36])(L + 107520 + w * 1152);

#define HANDOFF(ACC, TROW)                                                   \
  {                                                                          \
    _Pragma("unroll")                                                        \
    for (int nt = 0; nt < 4; ++nt) {                                         \
      f32x4 a = ACC[nt];                                                     \
      unsigned p0 = f2bf(a[0]) | (f2bf(a[1]) << 16);                         \
      unsigned p1 = f2bf(a[2]) | (f2bf(a[3]) << 16);                         \
      *(uint2*)&QL[TROW][nt * 16 + quad * 4] = (uint2){p0, p1};              \
    }                                                                        \
    _Pragma("unroll")                                                        \
    for (int nt = 4; nt < 8; ++nt) {                                         \
      f32x4 a = ACC[nt];                                                     \
      unsigned p0 = f2bf(a[0]) | (f2bf(a[1]) << 16);                         \
      unsigned p1 = f2bf(a[2]) | (f2bf(a[3]) << 16);                         \
      *(uint2*)&KL[TROW][(nt - 4) * 16 + quad * 4] = (uint2){p0, p1};        \
    }                                                                        \
    _Pragma("unroll")                                                        \
    for (int nt = 8; nt < 12; ++nt) {                                        \
      f32x4 a = ACC[nt];                                                     \
      const int h = (nt - 8) * 16 + quad * 4;                                \
      _Pragma("unroll")                                                      \
      for (int i = 0; i < 4; ++i)                                            \
        VT[h + i][TROW] = (unsigned short)f2bf(a[i]);                        \
    }                                                                        \
  }

  {
    const int trow0 = w * 32 + ln15;
    const int trow1 = trow0 + 16;
    HANDOFF(acc0, trow0)
    HANDOFF(acc1, trow1)
  }
  __syncthreads();

  // ---- attention: wave w does m-tiles {w, 15-w} (r7-verified) ------------
  for (int mi = 0; mi < 2; ++mi) {
    const int mt = mi ? (15 - w) : w;
    const int t0 = mt * 16;
    const int NT = (mt | 1) + 1;                 // even # of 16-wide s-tiles

    bf16x8 aq[2];
    #pragma unroll
    for (int ks = 0; ks < 2; ++ks)
      aq[ks] = *(const bf16x8*)&QL[t0 + ln15][ks * 32 + quad * 8];

    float sv[16][4];
    #pragma unroll
    for (int nt = 0; nt < 16; ++nt) {
      if (nt < NT) {
        f32x4 a2 = (f32x4){0.f, 0.f, 0.f, 0.f};
        #pragma unroll
        for (int ks = 0; ks < 2; ++ks) {
          bf16x8 bf = *(const bf16x8*)&KL[nt * 16 + ln15][ks * 32 + quad * 8];
          a2 = __builtin_amdgcn_mfma_f32_16x16x32_bf16(aq[ks], bf, a2, 0, 0, 0);
        }
        int colg = nt * 16 + ln15;
        #pragma unroll
        for (int i = 0; i < 4; ++i) {
          int rowg = t0 + quad * 4 + i;
          sv[nt][i] = (colg <= rowg) ? a2[i] * 0.125f : -3.0e38f;   // 1/sqrt(64)
        }
      }
    }
    float mx[4] = {-3.0e38f, -3.0e38f, -3.0e38f, -3.0e38f};
    #pragma unroll
    for (int nt = 0; nt < 16; ++nt)
      if (nt < NT) {
        #pragma unroll
        for (int i = 0; i < 4; ++i) mx[i] = fmaxf(mx[i], sv[nt][i]);
      }
    #pragma unroll
    for (int i = 0; i < 4; ++i) {                // reduce across 16-lane group
      mx[i] = fmaxf(mx[i], __shfl_xor(mx[i], 8, 64));
      mx[i] = fmaxf(mx[i], __shfl_xor(mx[i], 4, 64));
      mx[i] = fmaxf(mx[i], __shfl_xor(mx[i], 2, 64));
      mx[i] = fmaxf(mx[i], __shfl_xor(mx[i], 1, 64));
    }
    float sm[4] = {0.f, 0.f, 0.f, 0.f};
    #pragma unroll
    for (int nt = 0; nt < 16; ++nt)
      if (nt < NT) {
        #pragma unroll
        for (int i = 0; i < 4; ++i) {
          float e = __expf(sv[nt][i] - mx[i]);
          sv[nt][i] = e;
          sm[i] += e;
        }
      }
    #pragma unroll
    for (int i = 0; i < 4; ++i) {
      sm[i] += __shfl_xor(sm[i], 8, 64);
      sm[i] += __shfl_xor(sm[i], 4, 64);
      sm[i] += __shfl_xor(sm[i], 2, 64);
      sm[i] += __shfl_xor(sm[i], 1, 64);
    }
    float inv[4];
    #pragma unroll
    for (int i = 0; i < 4; ++i) inv[i] = 1.0f / sm[i];

    // PV in 32-wide K chunks via the wave-private P buffer (DS in-order).
    f32x4 o[4];
    #pragma unroll
    for (int ont = 0; ont < 4; ++ont) o[ont] = (f32x4){0.f, 0.f, 0.f, 0.f};

    #pragma unroll
    for (int kc = 0; kc < 8; ++kc) {
      if (kc * 2 < NT) {
        #pragma unroll
        for (int half = 0; half < 2; ++half) {
          int nt = kc * 2 + half;
          #pragma unroll
          for (int i = 0; i < 4; ++i)
            PL[quad * 4 + i][half * 16 + ln15] =
                (unsigned short)f2bf(sv[nt][i] * inv[i]);
        }
        bf16x8 pa = *(const bf16x8*)&PL[ln15][quad * 8];
        #pragma unroll
        for (int ont = 0; ont < 4; ++ont) {
          bf16x8 vb = *(const bf16x8*)&VT[ont * 16 + ln15][kc * 32 + quad * 8];
          o[ont] = __builtin_amdgcn_mfma_f32_16x16x32_bf16(pa, vb, o[ont], 0, 0, 0);
        }
      }
    }

    #pragma unroll
    for (int ont = 0; ont < 4; ++ont) {
      int h = ont * 16 + ln15;
      #pragma unroll
      for (int i = 0; i < 4; ++i)
        out[(size_t)(b * 256 + t0 + quad * 4 + i) * HDIM + h] = o[ont][i];
    }
  }
}

// ---------------------------------------------------------------------------
// ws layout: only WTf (147456 B).
// ---------------------------------------------------------------------------
extern "C" void kernel_launch(void* const* d_in, const int* in_sizes, int n_in,
                              void* d_out, int out_size, void* d_ws, size_t ws_size,
                              hipStream_t stream) {
  const float* x  = (const float*)d_in[0];
  const float* Wk = (const float*)d_in[1];
  const float* Wq = (const float*)d_in[2];
  const float* Wv = (const float*)d_in[3];
  float* out = (float*)d_out;

  unsigned short* WTf = (unsigned short*)d_ws;   // 147456 B

  wtrans_kernel<<<(192 * CDIM + 255) / 256, 256, 0, stream>>>(Wk, Wq, Wv, WTf);
  fused_kernel<<<256, 512, 0, stream>>>(x, WTf, out);
}

// Round 12
// 169.986 us; speedup vs baseline: 1.0822x; 1.0128x over previous
//
#include <hip/hip_runtime.h>

#define BATCH 256
#define SEQ   256
#define CDIM  384
#define HDIM  64

typedef __attribute__((ext_vector_type(8))) short bf16x8;
typedef __attribute__((ext_vector_type(4))) float f32x4;

__device__ __forceinline__ unsigned f2bf(float f) {
  union { float f; unsigned u; } v; v.f = f;
  unsigned r = v.u + 0x7FFFu + ((v.u >> 16) & 1u);   // RNE
  return r >> 16;
}

// ---------------------------------------------------------------------------
// kernel 0: WTf = [Wq|Wk|Wv]^T in MFMA fragment order.
//   frag record (ks,nt) = 64 lanes x 16 B; lane (ln15 + 16*quad) holds
//   WT row (nt*16+ln15), cols ks*32+quad*8 .. +7.
// ---------------------------------------------------------------------------
__global__ void wtrans_kernel(const float* __restrict__ Wk, const float* __restrict__ Wq,
                              const float* __restrict__ Wv, unsigned short* __restrict__ WTf) {
  int gid = blockIdx.x * 256 + threadIdx.x;
  if (gid >= 192 * CDIM) return;
  int n = gid / CDIM, kk = gid - n * CDIM;
  const float* W = (n < 64) ? Wq : (n < 128) ? Wk : Wv;
  int nt = n >> 4, ln = n & 15, ks = kk >> 5, sub = (kk >> 3) & 3, j = kk & 7;
  int lane = ln + 16 * sub;
  WTf[(((size_t)ks * 12 + nt) * 64 + lane) * 8 + j] =
      (unsigned short)f2bf(W[kk * HDIM + (n & 63)]);
}

// ---------------------------------------------------------------------------
// kernel 1: fused proj+attention — FINAL (best-measured configuration, r9).
//   Proj = r3-verified pipeline: W staged once via global_load_lds (async,
//   oldest in vmcnt FIFO), x depth-2 VGPR ping-pong, counted vmcnt(6) + raw
//   s_barrier so x chunk 0 rides across the W drain; 16 waves = 4/SIMD.
//   Attention = balanced no-max split: tiles 10..15 split between owner and
//   helper (15-w), partials merged via the dead QL region; every wave does
//   8-10 NT-units.  Measured 169.0 us total, absmax 0.0234375.
//   Structural floor note: 6 further levers (DMA stream, desync+setprio,
//   fat waves, 2-block residency, deeper prefetch, tail balance) measured
//   neutral-to-negative (rounds 4-11); fused sits <20% on all pipes with
//   ~112 us of the total being harness-fixed overhead.
// ---------------------------------------------------------------------------
__global__ __launch_bounds__(1024, 4) void fused_kernel(
    const float* __restrict__ x, const unsigned short* __restrict__ WTf,
    float* __restrict__ out) {
  __shared__ __align__(16) unsigned short lds[73728];   // 147456 B
  const int tid = threadIdx.x, b = blockIdx.x;
  const int w = tid >> 6, lane = tid & 63;
  const int ln15 = lane & 15, quad = lane >> 4;

  // ---- 1. W frags -> LDS: async DMA, 9 x 1KB chunks per wave (issued 1st)
  {
    const uint4* src = (const uint4*)WTf;
    #pragma unroll
    for (int i = 0; i < 9; ++i) {
      int c = i * 1024 + tid;
      __builtin_amdgcn_global_load_lds(
          (const __attribute__((address_space(1))) unsigned*)(src + c),
          (__attribute__((address_space(3))) unsigned*)((char*)lds + (size_t)c * 16),
          16, 0, 0);
    }
  }
  __builtin_amdgcn_sched_barrier(0);   // pin: DMAs are the 9 OLDEST vmem ops

  const float* xr = x + (size_t)(b * 256 + w * 16 + ln15) * CDIM + quad * 8;

  // stage buffers: 3 ks per stage = 6 float4
  float4 P0[6], P1[6];

#define LOADST(BUF, BASE)                                                    \
  {                                                                          \
    _Pragma("unroll")                                                        \
    for (int j = 0; j < 3; ++j) {                                            \
      BUF[2 * j]     = *(const float4*)(xr + (BASE + j) * 32);               \
      BUF[2 * j + 1] = *(const float4*)(xr + (BASE + j) * 32 + 4);           \
    }                                                                        \
  }

#define USEST(BUF, BASE)                                                     \
  {                                                                          \
    _Pragma("unroll")                                                        \
    for (int k2 = 0; k2 < 3; ++k2) {                                         \
      float4 a0 = BUF[2 * k2], a1 = BUF[2 * k2 + 1];                         \
      bf16x8 t;                                                              \
      t[0] = (short)f2bf(a0.x); t[1] = (short)f2bf(a0.y);                    \
      t[2] = (short)f2bf(a0.z); t[3] = (short)f2bf(a0.w);                    \
      t[4] = (short)f2bf(a1.x); t[5] = (short)f2bf(a1.y);                    \
      t[6] = (short)f2bf(a1.z); t[7] = (short)f2bf(a1.w);                    \
      _Pragma("unroll")                                                      \
      for (int nt = 0; nt < 12; ++nt) {                                      \
        bf16x8 aw = *(const bf16x8*)&lds[(((BASE + k2) * 12 + nt) * 64 + lane) * 8]; \
        acc[nt] = __builtin_amdgcn_mfma_f32_16x16x32_bf16(aw, t, acc[nt], 0, 0, 0);  \
      }                                                                      \
    }                                                                        \
  }

  // ---- 2. preload x chunk 0 (stays in flight across the W barrier) -------
  LOADST(P0, 0)
  __builtin_amdgcn_sched_barrier(0);

  asm volatile("s_waitcnt vmcnt(6)" ::: "memory");
  __builtin_amdgcn_s_barrier();
  __builtin_amdgcn_sched_barrier(0);

  // ---- 3. pipelined proj: consume stage s while stage s+1 streams --------
  f32x4 acc[12];
  #pragma unroll
  for (int nt = 0; nt < 12; ++nt) acc[nt] = (f32x4){0.f, 0.f, 0.f, 0.f};

  LOADST(P1, 3)
  USEST(P0, 0)
  LOADST(P0, 6)
  USEST(P1, 3)
  LOADST(P1, 9)
  USEST(P0, 6)
  USEST(P1, 9)

  __syncthreads();            // all waves done reading W -> LDS reusable

  // ---- 4. handoff: q/k/v -> LDS (aliased over the dead W region) ---------
  unsigned short (*QL)[72]  = (unsigned short(*)[72])lds;                 // bytes [0,36864)
  unsigned short (*KL)[72]  = (unsigned short(*)[72])(lds + 18432);       // [36864,73728)
  unsigned short (*VT)[264] = (unsigned short(*)[264])(lds + 36864);      // [73728,107520)
  unsigned short (*PL)[36]  = (unsigned short(*)[36])(lds + 53760 + w * 576); // [107520,...)

  {
    const int trow = w * 16 + ln15;              // C-frag: t indexed by ln15
    #pragma unroll
    for (int nt = 0; nt < 4; ++nt) {             // q
      f32x4 a = acc[nt];
      unsigned p0 = f2bf(a[0]) | (f2bf(a[1]) << 16);
      unsigned p1 = f2bf(a[2]) | (f2bf(a[3]) << 16);
      *(uint2*)&QL[trow][nt * 16 + quad * 4] = (uint2){p0, p1};
    }
    #pragma unroll
    for (int nt = 4; nt < 8; ++nt) {             // k
      f32x4 a = acc[nt];
      unsigned p0 = f2bf(a[0]) | (f2bf(a[1]) << 16);
      unsigned p1 = f2bf(a[2]) | (f2bf(a[3]) << 16);
      *(uint2*)&KL[trow][(nt - 4) * 16 + quad * 4] = (uint2){p0, p1};
    }
    #pragma unroll
    for (int nt = 8; nt < 12; ++nt) {            // v -> VT[h][t]
      f32x4 a = acc[nt];
      const int h = (nt - 8) * 16 + quad * 4;
      #pragma unroll
      for (int i = 0; i < 4; ++i)
        VT[h + i][trow] = (unsigned short)f2bf(a[i]);
    }
  }
  __syncthreads();

  // ---- 5. attention: balanced no-max split -------------------------------
  {
    const int uo = (w | 1) + 1;                  // own tile NT (even)
    const int nA = (uo < 10) ? uo : 10;          // own job size (head)
    const int mtB = 15 - w;                      // helper target (only w<6)
    const int nB = (w < 6) ? (((mtB | 1) + 1) - 10) : 0;   // 6,6,4,4,2,2

    bf16x8 aqA[2], aqB[2];
    #pragma unroll
    for (int ks = 0; ks < 2; ++ks) {
      aqA[ks] = *(const bf16x8*)&QL[w * 16 + ln15][ks * 32 + quad * 8];
      aqB[ks] = *(const bf16x8*)&QL[mtB * 16 + ln15][ks * 32 + quad * 8];
    }
    asm volatile("s_waitcnt lgkmcnt(0)" ::: "memory");
    __builtin_amdgcn_s_barrier();                // QL dead -> partial slots
    __builtin_amdgcn_sched_barrier(0);

    float* PB = (float*)lds;     // 6 slots x 1280 f32 (5120 B) = 30720 B

    float sv[10][4];
    float sm[4] = {0.f, 0.f, 0.f, 0.f};
    f32x4 o[4];
    #pragma unroll
    for (int t = 0; t < 4; ++t) o[t] = (f32x4){0.f, 0.f, 0.f, 0.f};

    // one job: QK^T over nt in [N0, N0+CNT), no-max exp, unnormalized PV.
#define AJOB(AQ, MT, N0, CNT)                                                 \
    {                                                                         \
      _Pragma("unroll")                                                       \
      for (int j = 0; j < 10; ++j) {                                          \
        if (j < (CNT)) {                                                      \
          const int nt = (N0) + j;                                            \
          f32x4 a2 = (f32x4){0.f, 0.f, 0.f, 0.f};                             \
          _Pragma("unroll")                                                   \
          for (int ks = 0; ks < 2; ++ks) {                                    \
            bf16x8 bf = *(const bf16x8*)&KL[nt * 16 + ln15][ks * 32 + quad * 8]; \
            a2 = __builtin_amdgcn_mfma_f32_16x16x32_bf16((AQ)[ks], bf, a2, 0, 0, 0); \
          }                                                                   \
          const int colg = nt * 16 + ln15;                                    \
          _Pragma("unroll")                                                   \
          for (int i = 0; i < 4; ++i) {                                       \
            const int rowg = (MT) * 16 + quad * 4 + i;                        \
            float e = (colg <= rowg) ? __expf(a2[i] * 0.125f) : 0.f;          \
            sv[j][i] = e;                                                     \
            sm[i] += e;                                                       \
          }                                                                   \
        }                                                                     \
      }                                                                       \
      _Pragma("unroll")                                                       \
      for (int kc = 0; kc < 5; ++kc) {                                        \
        if (kc * 2 < (CNT)) {                                                 \
          _Pragma("unroll")                                                   \
          for (int half = 0; half < 2; ++half) {                              \
            _Pragma("unroll")                                                 \
            for (int i = 0; i < 4; ++i)                                       \
              PL[quad * 4 + i][half * 16 + ln15] =                            \
                  (unsigned short)f2bf(sv[kc * 2 + half][i]);                 \
          }                                                                   \
          bf16x8 pa = *(const bf16x8*)&PL[ln15][quad * 8];                    \
          _Pragma("unroll")                                                   \
          for (int ont = 0; ont < 4; ++ont) {                                 \
            bf16x8 vb = *(const bf16x8*)&VT[ont * 16 + ln15][((N0) + kc * 2) * 16 + quad * 8]; \
            o[ont] = __builtin_amdgcn_mfma_f32_16x16x32_bf16(pa, vb, o[ont], 0, 0, 0); \
          }                                                                   \
        }                                                                     \
      }                                                                       \
    }

    if (w < 6) {                 // helper job FIRST: tail of tile 15-w
      AJOB(aqB, mtB, 10, nB)
      float* slot = PB + (mtB - 10) * 1280;
      #pragma unroll
      for (int ont = 0; ont < 4; ++ont)
        *(f32x4*)(slot + lane * 16 + ont * 4) = o[ont];
      *(f32x4*)(slot + 1024 + lane * 4) = (f32x4){sm[0], sm[1], sm[2], sm[3]};
      #pragma unroll
      for (int i = 0; i < 4; ++i) sm[i] = 0.f;
      #pragma unroll
      for (int t = 0; t < 4; ++t) o[t] = (f32x4){0.f, 0.f, 0.f, 0.f};
    }

    AJOB(aqA, w, 0, nA)          // own job (full tile for w<10, head for w>=10)

    if (w < 10) {                // own tile complete: finalize + write out
      #pragma unroll
      for (int i = 0; i < 4; ++i) {
        sm[i] += __shfl_xor(sm[i], 8, 64);
        sm[i] += __shfl_xor(sm[i], 4, 64);
        sm[i] += __shfl_xor(sm[i], 2, 64);
        sm[i] += __shfl_xor(sm[i], 1, 64);
      }
      float inv[4];
      #pragma unroll
      for (int i = 0; i < 4; ++i) inv[i] = 1.0f / sm[i];
      #pragma unroll
      for (int ont = 0; ont < 4; ++ont) {
        int h = ont * 16 + ln15;
        #pragma unroll
        for (int i = 0; i < 4; ++i)
          out[(size_t)(b * 256 + w * 16 + quad * 4 + i) * HDIM + h] = o[ont][i] * inv[i];
      }
    }

    asm volatile("s_waitcnt lgkmcnt(0)" ::: "memory");   // partials landed
    __builtin_amdgcn_s_barrier();
    __builtin_amdgcn_sched_barrier(0);

    if (w >= 10) {               // merge helper tail, finalize + write out
      float* slot = PB + (w - 10) * 1280;
      #pragma unroll
      for (int ont = 0; ont < 4; ++ont) {
        f32x4 po = *(const f32x4*)(slot + lane * 16 + ont * 4);
        #pragma unroll
        for (int i = 0; i < 4; ++i) o[ont][i] += po[i];
      }
      f32x4 ps = *(const f32x4*)(slot + 1024 + lane * 4);
      #pragma unroll
      for (int i = 0; i < 4; ++i) sm[i] += ps[i];
      #pragma unroll
      for (int i = 0; i < 4; ++i) {
        sm[i] += __shfl_xor(sm[i], 8, 64);
        sm[i] += __shfl_xor(sm[i], 4, 64);
        sm[i] += __shfl_xor(sm[i], 2, 64);
        sm[i] += __shfl_xor(sm[i], 1, 64);
      }
      float inv[4];
      #pragma unroll
      for (int i = 0; i < 4; ++i) inv[i] = 1.0f / sm[i];
      #pragma unroll
      for (int ont = 0; ont < 4; ++ont) {
        int h = ont * 16 + ln15;
        #pragma unroll
        for (int i = 0; i < 4; ++i)
          out[(size_t)(b * 256 + w * 16 + quad * 4 + i) * HDIM + h] = o[ont][i] * inv[i];
      }
    }
  }
}

// ---------------------------------------------------------------------------
// ws layout: only WTf (147456 B).
// ---------------------------------------------------------------------------
extern "C" void kernel_launch(void* const* d_in, const int* in_sizes, int n_in,
                              void* d_out, int out_size, void* d_ws, size_t ws_size,
                              hipStream_t stream) {
  const float* x  = (const float*)d_in[0];
  const float* Wk = (const float*)d_in[1];
  const float* Wq = (const float*)d_in[2];
  const float* Wv = (const float*)d_in[3];
  float* out = (float*)d_out;

  unsigned short* WTf = (unsigned short*)d_ws;   // 147456 B

  wtrans_kernel<<<(192 * CDIM + 255) / 256, 256, 0, stream>>>(Wk, Wq, Wv, WTf);
  fused_kernel<<<256, 1024, 0, stream>>>(x, WTf, out);
}